// Round 8
// baseline (189.609 us; speedup 1.0000x reference)
//
#include <hip/hip_runtime.h>
#include <hip/hip_bf16.h>
#include <stdint.h>

#define NB 8
#define TT 2048
#define DD 1024
#define HDIM 64

typedef __bf16 bf16x8 __attribute__((ext_vector_type(8)));
typedef float f32x4 __attribute__((ext_vector_type(4)));

static_assert(sizeof(bf16x8) == 16, "bf16x8 must be 16 bytes");

__device__ inline ushort f2bf_bits(float f) {
    __hip_bfloat16 h = __float2bfloat16(f);
    return *reinterpret_cast<ushort*>(&h);
}
__device__ inline float bfbits2f(ushort u) {
    unsigned v = ((unsigned)u) << 16;
    return __builtin_bit_cast(float, v);
}
__device__ inline bf16x8 ldb8(const ushort* p) {
    return *reinterpret_cast<const bf16x8*>(p);
}

// async global->LDS DMA, 16B/lane: dest = wave-uniform base + lane*16.
typedef __attribute__((address_space(3))) uint32_t lds_u32;
typedef const __attribute__((address_space(1))) uint32_t glb_u32;
__device__ inline void gl_lds16(const void* g, void* l) {
    __builtin_amdgcn_global_load_lds((glb_u32*)g, (lds_u32*)l, 16, 0, 0);
}

// s_waitcnt immediates (gfx9 encoding: vm[3:0]+[15:14], exp[6:4], lgkm[11:8])
#define WCNT_VM8   0xF78   // vmcnt(8),  expcnt/lgkmcnt unconstrained
#define WCNT_VM7   0xF77   // vmcnt(7)
#define WCNT_LGKM0 0xC07F  // lgkmcnt(0), vmcnt/expcnt unconstrained

// ---------------------------------------------------------------------------
// Inline dtype probe: f32 x -> even halfwords show wild bf16 exponents.
// ---------------------------------------------------------------------------
__device__ inline int probe_f32(const ushort* x) {
    int lane = threadIdx.x & 63;
    int wild = 0;
    #pragma unroll
    for (int j = 0; j < 4; ++j) {
        ushort u = x[(lane * 4 + j) * 32];
        int e = (u >> 7) & 0xFF;
        wild += (e >= 0xC0);
    }
    unsigned long long m = __ballot(wild > 0);
    return __popcll(m) > 8;
}

// ---------------------------------------------------------------------------
// Kernel 1: pack weights -> Wt[3][64][1024] bf16 (n-major, k contiguous).
// Softmax scale * log2(e) folded into Wq (exp2 domain).
// ---------------------------------------------------------------------------
__global__ __launch_bounds__(256) void k_wt(const ushort* __restrict__ x,
                                            const void* __restrict__ Wq,
                                            const void* __restrict__ Wk,
                                            const void* __restrict__ Wv,
                                            ushort* __restrict__ Wt) {
    int f32m = probe_f32(x);
    int idx = blockIdx.x * 256 + threadIdx.x;   // 0 .. 196607
    int mat = idx >> 16;
    int rem = idx & 65535;                      // = d*64 + h
    int d = rem >> 6;
    int h = rem & 63;
    const void* W = (mat == 0) ? Wq : (mat == 1) ? Wk : Wv;
    float v;
    if (f32m) v = ((const float*)W)[rem];
    else      v = bfbits2f(((const ushort*)W)[rem]);
    if (mat == 0) v *= 0.18033688011112042f;    // 0.125 * log2(e)
    Wt[(size_t)mat * 65536 + (size_t)h * DD + d] = f2bf_bits(v);
}

// ---------------------------------------------------------------------------
// Kernel 2: QKV projection -- AITER-style K-loop: double-buffered LDS DMA
// with raw s_barrier + fine s_waitcnt (prefetch stays in flight across the
// barrier).  512 blocks x 4 waves; block = 32 rows x 192 cols; wave = 16
// rows (mt) x 96 cols (nh), 6 accs; K-chunk 64 (2 MFMA k-steps).
// F32M is a template param so waitcnt immediates are compile-time constants.
// ---------------------------------------------------------------------------
__shared__ ushort Bf_s[2][24][512];           // 48 KB: [buf][nt*2+ks][frag]
__shared__ float  Aff_s[2][2][2][2][256];     // 16 KB: [buf][mt][ks][half]
__shared__ ushort Afb_s[2][2][2][512];        //  8 KB: [buf][mt][ks]

template <int F32M>
__device__ inline void proj_body(const void* __restrict__ xv,
                                 const ushort* __restrict__ Wt,
                                 ushort* __restrict__ Qw,
                                 ushort* __restrict__ Kw,
                                 ushort* __restrict__ Vtw) {
    int tid  = threadIdx.x;
    int w    = tid >> 6;
    int lane = tid & 63;
    int quad = lane >> 4;
    int col  = lane & 15;
    int mt   = w >> 1;                    // m-tile within block
    int nh   = w & 1;                     // n-half
    int m0   = blockIdx.x * 32;

    auto stage = [&](int buf, int kkk) {
        #pragma unroll
        for (int j = 0; j < 6; ++j) {
            int f  = w * 6 + j;                // f = nt*2 + ks
            int nt = f >> 1, ks = f & 1;
            gl_lds16(Wt + (size_t)(nt * 16 + col) * DD + kkk + ks * 32 + quad * 8,
                     &Bf_s[buf][f][0]);
        }
        if (F32M) {
            #pragma unroll
            for (int j = 0; j < 2; ++j) {
                int a = w * 2 + j;             // a = mt*4 + ks*2 + half
                int amt = a >> 2, ks = (a >> 1) & 1, hf = a & 1;
                gl_lds16((const float*)xv + (size_t)(m0 + amt * 16 + col) * DD
                             + kkk + ks * 32 + hf * 4 + quad * 8,
                         &Aff_s[buf][amt][ks][hf][0]);
            }
        } else {
            int amt = w >> 1, ks = w & 1;      // a = mt*2 + ks = w
            gl_lds16((const ushort*)xv + (size_t)(m0 + amt * 16 + col) * DD
                         + kkk + ks * 32 + quad * 8,
                     &Afb_s[buf][amt][ks][0]);
        }
    };

    f32x4 acc[6];
    #pragma unroll
    for (int i = 0; i < 6; ++i) acc[i] = (f32x4){0.f,0.f,0.f,0.f};

    stage(0, 0);
    for (int kk = 0; kk < DD; kk += 64) {
        int p  = (kk >> 6) & 1;
        int kn = (kk + 64 < DD) ? kk + 64 : kk;      // clamped on last iter
        stage(p ^ 1, kn);
        if (F32M) __builtin_amdgcn_s_waitcnt(WCNT_VM8);  // own chunk-k DMAs done
        else      __builtin_amdgcn_s_waitcnt(WCNT_VM7);
        __builtin_amdgcn_s_barrier();                    // all waves' chunk-k done

        #pragma unroll
        for (int ks = 0; ks < 2; ++ks) {
            bf16x8 a;
            if (F32M) {
                f32x4 alo = *reinterpret_cast<const f32x4*>(&Aff_s[p][mt][ks][0][lane * 4]);
                f32x4 ahi = *reinterpret_cast<const f32x4*>(&Aff_s[p][mt][ks][1][lane * 4]);
                #pragma unroll
                for (int j = 0; j < 4; ++j) { a[j] = (__bf16)alo[j]; a[4+j] = (__bf16)ahi[j]; }
            } else {
                a = ldb8(&Afb_s[p][mt][ks][lane * 8]);
            }
            #pragma unroll
            for (int j = 0; j < 6; ++j) {
                int nt = nh * 6 + j;
                bf16x8 b = ldb8(&Bf_s[p][nt * 2 + ks][lane * 8]);
                acc[j] = __builtin_amdgcn_mfma_f32_16x16x32_bf16(a, b, acc[j], 0, 0, 0);
            }
        }
        __builtin_amdgcn_s_waitcnt(WCNT_LGKM0);      // reads of buf[p] complete
        __builtin_amdgcn_s_barrier();                // before buf[p] is re-staged
    }

    // C/D layout: row = quad*4 + reg, col = lane&15
    #pragma unroll
    for (int j = 0; j < 6; ++j) {
        int nt  = nh * 6 + j;
        int mat = nt >> 2;                 // 0=Q,1=K,2=V
        int h   = (nt & 3) * 16 + col;
        if (mat == 2) {
            #pragma unroll
            for (int r = 0; r < 4; ++r) {
                int row = m0 + mt * 16 + quad * 4 + r;
                int bb = row >> 11;
                int t  = row & (TT - 1);
                Vtw[(size_t)bb * HDIM * TT + (size_t)h * TT + t] = f2bf_bits(acc[j][r]);
            }
        } else {
            ushort* outp = (mat == 0) ? Qw : Kw;
            #pragma unroll
            for (int r = 0; r < 4; ++r) {
                int row = m0 + mt * 16 + quad * 4 + r;
                outp[(size_t)row * HDIM + h] = f2bf_bits(acc[j][r]);
            }
        }
    }
}

__global__ __launch_bounds__(256) void k_proj(const void* __restrict__ xv,
                                              const ushort* __restrict__ Wt,
                                              ushort* __restrict__ Qw,
                                              ushort* __restrict__ Kw,
                                              ushort* __restrict__ Vtw) {
    if (probe_f32((const ushort*)xv)) proj_body<1>(xv, Wt, Qw, Kw, Vtw);
    else                              proj_body<0>(xv, Wt, Qw, Kw, Vtw);
}

// ---------------------------------------------------------------------------
// Kernel 3: split-K causal flash attention (fixed-max exp2 domain), wave-
// private DOUBLE-BUFFERED K/V LDS: stage step i+1, wait vmcnt(8) for step i,
// no barriers.  640 blocks x 4 waves; wave = one (b, qb, 512-chunk).
// ---------------------------------------------------------------------------
__global__ __launch_bounds__(256) void k_attn(const ushort* __restrict__ Qw,
                                              const ushort* __restrict__ Kw,
                                              const ushort* __restrict__ Vtw,
                                              ushort* __restrict__ Po,
                                              float* __restrict__ Pl) {
    int w    = threadIdx.x >> 6;
    int lane = threadIdx.x & 63;
    int quad = lane >> 4;
    int col  = lane & 15;
    int gcid = blockIdx.x * 4 + w;         // 0..2559
    int b    = gcid & 7;
    int cid  = 319 - (gcid >> 3);          // long chunks first
    int qb, c;
    if (cid < 32)       { qb = cid;                 c = 0; }
    else if (cid < 96)  { int t = cid - 32;  qb = 32 + (t >> 1); c = t & 1; }
    else if (cid < 192) { int t = cid - 96;  qb = 64 + t / 3;    c = t - (qb - 64) * 3; }
    else                { int t = cid - 192; qb = 96 + (t >> 2); c = t & 3; }
    int pid = b * 320 + cid;
    int m0  = qb * 16;

    const ushort* Qb = Qw + (size_t)b * TT * HDIM;
    const ushort* Kb = Kw + (size_t)b * TT * HDIM;
    const ushort* Vb = Vtw + (size_t)b * HDIM * TT;

    __shared__ ushort KVf[4][2][8][512];       // 64 KB: per-wave double buffer
    __shared__ __hip_bfloat16 Pls[4][16][40];  //  5 KB: per-wave P roundtrip

    auto stageKV = [&](int buf, int s) {
        const ushort* k0 = Kb + (size_t)(s + col) * HDIM + quad * 8;
        const ushort* k1 = Kb + (size_t)(s + 16 + col) * HDIM + quad * 8;
        gl_lds16(k0,      &KVf[w][buf][0][0]);
        gl_lds16(k0 + 32, &KVf[w][buf][1][0]);
        gl_lds16(k1,      &KVf[w][buf][2][0]);
        gl_lds16(k1 + 32, &KVf[w][buf][3][0]);
        #pragma unroll
        for (int g = 0; g < 4; ++g)
            gl_lds16(Vb + (size_t)(g * 16 + col) * TT + s + quad * 8, &KVf[w][buf][4 + g][0]);
    };

    bf16x8 qf0 = ldb8(Qb + (size_t)(m0 + col) * HDIM + quad * 8);
    bf16x8 qf1 = ldb8(Qb + (size_t)(m0 + col) * HDIM + 32 + quad * 8);

    f32x4 o0 = {0.f,0.f,0.f,0.f};
    f32x4 o1 = {0.f,0.f,0.f,0.f};
    f32x4 o2 = {0.f,0.f,0.f,0.f};
    f32x4 o3 = {0.f,0.f,0.f,0.f};
    float rsum[4] = {0.f, 0.f, 0.f, 0.f};

    const int start = c * 512;
    const int end   = min(start + 512, m0 + 16);

    stageKV(0, start);
    for (int s0 = start; s0 < end; s0 += 32) {
        int p  = ((s0 - start) >> 5) & 1;
        int sn = (s0 + 32 < end) ? s0 + 32 : s0;
        __builtin_amdgcn_s_waitcnt(WCNT_LGKM0);  // prior reads of buf[p^1] done
        stageKV(p ^ 1, sn);                      // prefetch step i+1
        __builtin_amdgcn_s_waitcnt(WCNT_VM8);    // step i's 8 DMAs complete

        bf16x8 ck0l = ldb8(&KVf[w][p][0][lane * 8]);
        bf16x8 ck0h = ldb8(&KVf[w][p][1][lane * 8]);
        bf16x8 ck1l = ldb8(&KVf[w][p][2][lane * 8]);
        bf16x8 ck1h = ldb8(&KVf[w][p][3][lane * 8]);

        f32x4 S0 = {0.f,0.f,0.f,0.f};
        f32x4 S1 = {0.f,0.f,0.f,0.f};
        S0 = __builtin_amdgcn_mfma_f32_16x16x32_bf16(qf0, ck0l, S0, 0, 0, 0);
        S0 = __builtin_amdgcn_mfma_f32_16x16x32_bf16(qf1, ck0h, S0, 0, 0, 0);
        S1 = __builtin_amdgcn_mfma_f32_16x16x32_bf16(qf0, ck1l, S1, 0, 0, 0);
        S1 = __builtin_amdgcn_mfma_f32_16x16x32_bf16(qf1, ck1h, S1, 0, 0, 0);

        #pragma unroll
        for (int r = 0; r < 4; ++r) {
            int trow = m0 + quad * 4 + r;
            float aa = (s0 + col      > trow) ? -1e30f : S0[r];
            float dd = (s0 + 16 + col > trow) ? -1e30f : S1[r];
            float p0 = exp2f(aa);
            float p1 = exp2f(dd);
            rsum[r] += p0 + p1;
            Pls[w][quad * 4 + r][col]      = __float2bfloat16(p0);
            Pls[w][quad * 4 + r][16 + col] = __float2bfloat16(p1);
        }
        bf16x8 pf = *reinterpret_cast<const bf16x8*>(&Pls[w][col][quad * 8]);

        bf16x8 cv0 = ldb8(&KVf[w][p][4][lane * 8]);
        bf16x8 cv1 = ldb8(&KVf[w][p][5][lane * 8]);
        bf16x8 cv2 = ldb8(&KVf[w][p][6][lane * 8]);
        bf16x8 cv3 = ldb8(&KVf[w][p][7][lane * 8]);
        o0 = __builtin_amdgcn_mfma_f32_16x16x32_bf16(pf, cv0, o0, 0, 0, 0);
        o1 = __builtin_amdgcn_mfma_f32_16x16x32_bf16(pf, cv1, o1, 0, 0, 0);
        o2 = __builtin_amdgcn_mfma_f32_16x16x32_bf16(pf, cv2, o2, 0, 0, 0);
        o3 = __builtin_amdgcn_mfma_f32_16x16x32_bf16(pf, cv3, o3, 0, 0, 0);
    }

    #pragma unroll
    for (int off = 1; off < 16; off <<= 1) {
        #pragma unroll
        for (int r = 0; r < 4; ++r)
            rsum[r] += __shfl_xor(rsum[r], off, 64);
    }

    ushort* pb = Po + (size_t)pid * 1024;
    #pragma unroll
    for (int r = 0; r < 4; ++r) {
        int row = quad * 4 + r;
        pb[row * 64 + 0*16 + col] = f2bf_bits(o0[r]);
        pb[row * 64 + 1*16 + col] = f2bf_bits(o1[r]);
        pb[row * 64 + 2*16 + col] = f2bf_bits(o2[r]);
        pb[row * 64 + 3*16 + col] = f2bf_bits(o3[r]);
        if (col == 0) Pl[pid * 16 + row] = rsum[r];
    }
}

// ---------------------------------------------------------------------------
// Kernel 4: merge <=4 chunk partials (plain sum, shared implicit max=0),
// normalize by total L, store out.  One wave per (b,qb).
// ---------------------------------------------------------------------------
__global__ __launch_bounds__(256) void k_merge(const ushort* __restrict__ x,
                                               const ushort* __restrict__ Po,
                                               const float* __restrict__ Pl,
                                               void* __restrict__ outv) {
    int f32m = probe_f32(x);
    int wid  = blockIdx.x * 4 + (threadIdx.x >> 6);  // 0..1023
    int lane = threadIdx.x & 63;
    int row  = lane >> 2;
    int g    = lane & 3;
    int b    = wid >> 7;
    int qb   = wid & 127;
    int nch  = (qb >> 5) + 1;
    int Bq   = (qb < 32) ? qb : (qb < 64) ? 2*qb - 32 : (qb < 96) ? 3*qb - 96 : 4*qb - 192;
    int pid0 = b * 320 + Bq;

    float L = 0.f;
    #pragma unroll
    for (int c = 0; c < 4; ++c)
        if (c < nch) L += Pl[(pid0 + c) * 16 + row];
    float inv = 1.0f / L;

    float o[16];
    #pragma unroll
    for (int j = 0; j < 16; ++j) o[j] = 0.f;
    #pragma unroll
    for (int c = 0; c < 4; ++c) {
        if (c < nch) {
            const ushort* p = Po + (size_t)(pid0 + c) * 1024 + row * 64 + g * 16;
            bf16x8 v0 = ldb8(p);
            bf16x8 v1 = ldb8(p + 8);
            #pragma unroll
            for (int j = 0; j < 8; ++j) {
                o[j]     += (float)v0[j];
                o[8 + j] += (float)v1[j];
            }
        }
    }

    size_t obase = ((size_t)b * TT + qb * 16 + row) * HDIM + g * 16;
    if (f32m) {
        float* ob = (float*)outv + obase;
        #pragma unroll
        for (int j = 0; j < 16; ++j) ob[j] = o[j] * inv;
    } else {
        ushort* ob = (ushort*)outv + obase;
        #pragma unroll
        for (int j = 0; j < 16; ++j) ob[j] = f2bf_bits(o[j] * inv);
    }
}

// ---------------------------------------------------------------------------
extern "C" void kernel_launch(void* const* d_in, const int* in_sizes, int n_in,
                              void* d_out, int out_size, void* d_ws, size_t ws_size,
                              hipStream_t stream) {
    const ushort* x = (const ushort*)d_in[0];
    ushort* Wt  = (ushort*)d_ws;                       // 196608 elts
    ushort* Qw  = Wt + 3 * HDIM * DD;
    ushort* Kw  = Qw + (size_t)NB * TT * HDIM;
    ushort* Vtw = Kw + (size_t)NB * TT * HDIM;
    ushort* Po  = Vtw + (size_t)NB * TT * HDIM;        // 2560*1024 ushorts
    float*  Pl  = (float*)(Po + (size_t)2560 * 1024);  // ~12.2 MB total

    k_wt   <<<768, 256, 0, stream>>>(x, d_in[1], d_in[2], d_in[3], Wt);
    k_proj <<<512, 256, 0, stream>>>(d_in[0], Wt, Qw, Kw, Vtw);
    k_attn <<<640, 256, 0, stream>>>(Qw, Kw, Vtw, Po, Pl);
    k_merge<<<256, 256, 0, stream>>>(x, Po, Pl, d_out);
}

// Round 9
// 158.527 us; speedup vs baseline: 1.1961x; 1.1961x over previous
//
#include <hip/hip_runtime.h>
#include <hip/hip_bf16.h>
#include <stdint.h>

#define NB 8
#define TT 2048
#define DD 1024
#define HDIM 64

typedef __bf16 bf16x8 __attribute__((ext_vector_type(8)));
typedef float f32x4 __attribute__((ext_vector_type(4)));

static_assert(sizeof(bf16x8) == 16, "bf16x8 must be 16 bytes");

__device__ inline ushort f2bf_bits(float f) {
    __hip_bfloat16 h = __float2bfloat16(f);
    return *reinterpret_cast<ushort*>(&h);
}
__device__ inline float bfbits2f(ushort u) {
    unsigned v = ((unsigned)u) << 16;
    return __builtin_bit_cast(float, v);
}
__device__ inline bf16x8 ldb8(const ushort* p) {
    return *reinterpret_cast<const bf16x8*>(p);
}

// async global->LDS DMA, 16B/lane: dest = wave-uniform base + lane*16.
typedef __attribute__((address_space(3))) uint32_t lds_u32;
typedef const __attribute__((address_space(1))) uint32_t glb_u32;
__device__ inline void gl_lds16(const void* g, void* l) {
    __builtin_amdgcn_global_load_lds((glb_u32*)g, (lds_u32*)l, 16, 0, 0);
}

// s_waitcnt immediates (gfx9: vm[3:0]+[15:14], exp[6:4], lgkm[11:8])
#define WCNT_VM2   0xF72   // vmcnt(2)
#define WCNT_VM4   0xF74   // vmcnt(4)
#define WCNT_VM6   0xF76   // vmcnt(6)
#define WCNT_LGKM0 0xC07F  // lgkmcnt(0), vmcnt/expcnt unconstrained

// ---------------------------------------------------------------------------
// Inline dtype probe: f32 x -> even halfwords show wild bf16 exponents.
// ---------------------------------------------------------------------------
__device__ inline int probe_f32(const ushort* x) {
    int lane = threadIdx.x & 63;
    int wild = 0;
    #pragma unroll
    for (int j = 0; j < 4; ++j) {
        ushort u = x[(lane * 4 + j) * 32];
        int e = (u >> 7) & 0xFF;
        wild += (e >= 0xC0);
    }
    unsigned long long m = __ballot(wild > 0);
    return __popcll(m) > 8;
}

// ---------------------------------------------------------------------------
// Kernel 1: pack weights -> Wt[192][1024] bf16 (row = global out-col, k
// contiguous).  Softmax scale * log2(e) folded into Wq (exp2 domain).
// ---------------------------------------------------------------------------
__global__ __launch_bounds__(256) void k_wt(const ushort* __restrict__ x,
                                            const void* __restrict__ Wq,
                                            const void* __restrict__ Wk,
                                            const void* __restrict__ Wv,
                                            ushort* __restrict__ Wt) {
    int f32m = probe_f32(x);
    int idx = blockIdx.x * 256 + threadIdx.x;   // 0 .. 196607
    int mat = idx >> 16;
    int rem = idx & 65535;                      // = d*64 + h
    int d = rem >> 6;
    int h = rem & 63;
    const void* W = (mat == 0) ? Wq : (mat == 1) ? Wk : Wv;
    float v;
    if (f32m) v = ((const float*)W)[rem];
    else      v = bfbits2f(((const ushort*)W)[rem]);
    if (mat == 0) v *= 0.18033688011112042f;    // 0.125 * log2(e)
    Wt[(size_t)mat * 65536 + (size_t)h * DD + d] = f2bf_bits(v);
}

// ---------------------------------------------------------------------------
// Kernel 2: QKV projection.  768 blocks = 256 m-blocks(64 rows) x 3 n-tiles
// (64 cols = exactly one of Q/K/V).  4 waves; wave = 16 rows x 64 cols
// (4 accs).  BK=64 double-buffered LDS DMA, vmcnt-crossing-barrier.
// LDS 48 KB -> 3 blocks/CU via grid, ~12 waves/CU.
// ---------------------------------------------------------------------------
template <int F32M>
__device__ inline void proj_body(const void* __restrict__ xv,
                                 const ushort* __restrict__ Wt,
                                 ushort* __restrict__ Qw,
                                 ushort* __restrict__ Kw,
                                 ushort* __restrict__ Vtw,
                                 ushort* Bf, ushort* Af) {
    int tid  = threadIdx.x;
    int w    = tid >> 6;
    int lane = tid & 63;
    int quad = lane >> 4;
    int col  = lane & 15;
    int mblk = blockIdx.x / 3;
    int nt3  = blockIdx.x % 3;           // 0=Q, 1=K, 2=V
    int m0   = mblk * 64;

    // Bf: [buf][ks][j][512] ushort (16 KB); Af: f32 [buf][mt][ks][hf][256]
    // (32 KB) or bf16 [buf][mt][ks][512] (16 KB, aliased).
    auto stage = [&](int buf, int kkk) {
        #pragma unroll
        for (int ks = 0; ks < 2; ++ks)
            gl_lds16(Wt + (size_t)(nt3 * 64 + w * 16 + col) * DD + kkk + ks * 32 + quad * 8,
                     Bf + (((buf * 2 + ks) * 4) + w) * 512);
        if (F32M) {
            const float* xf = (const float*)xv;
            #pragma unroll
            for (int ks = 0; ks < 2; ++ks)
                #pragma unroll
                for (int hf = 0; hf < 2; ++hf)
                    gl_lds16(xf + (size_t)(m0 + w * 16 + col) * DD + kkk + ks * 32 + hf * 4 + quad * 8,
                             (float*)Af + ((((buf * 4 + w) * 2 + ks) * 2) + hf) * 256);
        } else {
            const ushort* xb = (const ushort*)xv;
            #pragma unroll
            for (int ks = 0; ks < 2; ++ks)
                gl_lds16(xb + (size_t)(m0 + w * 16 + col) * DD + kkk + ks * 32 + quad * 8,
                         Af + ((buf * 4 + w) * 2 + ks) * 512);
        }
    };

    f32x4 acc[4];
    #pragma unroll
    for (int i = 0; i < 4; ++i) acc[i] = (f32x4){0.f,0.f,0.f,0.f};

    stage(0, 0);
    for (int kk = 0; kk < DD; kk += 64) {
        int p  = (kk >> 6) & 1;
        int kn = (kk + 64 < DD) ? kk + 64 : kk;
        stage(p ^ 1, kn);
        if (F32M) __builtin_amdgcn_s_waitcnt(WCNT_VM6);   // own 6 chunk-k DMAs done
        else      __builtin_amdgcn_s_waitcnt(WCNT_VM4);
        __builtin_amdgcn_s_barrier();

        #pragma unroll
        for (int ks = 0; ks < 2; ++ks) {
            bf16x8 a;
            if (F32M) {
                const float* Afp = (const float*)Af;
                f32x4 alo = *reinterpret_cast<const f32x4*>(Afp + ((((p * 4 + w) * 2 + ks) * 2) + 0) * 256 + lane * 4);
                f32x4 ahi = *reinterpret_cast<const f32x4*>(Afp + ((((p * 4 + w) * 2 + ks) * 2) + 1) * 256 + lane * 4);
                #pragma unroll
                for (int j = 0; j < 4; ++j) { a[j] = (__bf16)alo[j]; a[4+j] = (__bf16)ahi[j]; }
            } else {
                a = ldb8(Af + ((p * 4 + w) * 2 + ks) * 512 + lane * 8);
            }
            #pragma unroll
            for (int j = 0; j < 4; ++j) {
                bf16x8 b = ldb8(Bf + (((p * 2 + ks) * 4) + j) * 512 + lane * 8);
                acc[j] = __builtin_amdgcn_mfma_f32_16x16x32_bf16(a, b, acc[j], 0, 0, 0);
            }
        }
        __builtin_amdgcn_s_waitcnt(WCNT_LGKM0);   // buf[p] reads complete
        __builtin_amdgcn_s_barrier();             // before buf[p] re-stage
    }

    // C/D layout: row = quad*4 + reg, col = lane&15; mat == nt3
    if (nt3 == 2) {
        #pragma unroll
        for (int j = 0; j < 4; ++j) {
            int h = j * 16 + col;
            #pragma unroll
            for (int r = 0; r < 4; ++r) {
                int row = m0 + w * 16 + quad * 4 + r;
                int bb = row >> 11;
                int t  = row & (TT - 1);
                Vtw[(size_t)bb * HDIM * TT + (size_t)h * TT + t] = f2bf_bits(acc[j][r]);
            }
        }
    } else {
        ushort* outp = (nt3 == 0) ? Qw : Kw;
        #pragma unroll
        for (int j = 0; j < 4; ++j) {
            int h = j * 16 + col;
            #pragma unroll
            for (int r = 0; r < 4; ++r) {
                int row = m0 + w * 16 + quad * 4 + r;
                outp[(size_t)row * HDIM + h] = f2bf_bits(acc[j][r]);
            }
        }
    }
}

__global__ __launch_bounds__(256) void k_proj(const void* __restrict__ xv,
                                              const ushort* __restrict__ Wt,
                                              ushort* __restrict__ Qw,
                                              ushort* __restrict__ Kw,
                                              ushort* __restrict__ Vtw) {
    __shared__ ushort Bf[2 * 2 * 4 * 512];    // 16 KB
    __shared__ float  Af[2 * 4 * 2 * 2 * 256];// 32 KB (bf16 path aliases)
    if (probe_f32((const ushort*)xv)) proj_body<1>(xv, Wt, Qw, Kw, Vtw, Bf, (ushort*)Af);
    else                              proj_body<0>(xv, Wt, Qw, Kw, Vtw, Bf, (ushort*)Af);
}

// ---------------------------------------------------------------------------
// Kernel 3: split-K causal flash attention, BLOCK-SHARED K/V staging.
// Block = (b, q-group of 4 tiles, 512-key chunk); 4 waves each own one
// q-tile, sharing one double-buffered K/V stream (16 KB).  2 DMAs/wave/step,
// vmcnt(2) across barrier.  640 blocks, ~21 KB LDS -> all co-resident.
// ---------------------------------------------------------------------------
__global__ __launch_bounds__(256) void k_attn(const ushort* __restrict__ Qw,
                                              const ushort* __restrict__ Kw,
                                              const ushort* __restrict__ Vtw,
                                              ushort* __restrict__ Po,
                                              float* __restrict__ Pl) {
    int w    = threadIdx.x >> 6;
    int lane = threadIdx.x & 63;
    int quad = lane >> 4;
    int col  = lane & 15;
    int bid  = blockIdx.x;               // 0..639
    int b    = bid & 7;
    int idx  = 79 - (bid >> 3);          // longer blocks earlier-ish
    int c, g;
    if (idx < 32)      { c = 0; g = idx; }
    else if (idx < 56) { c = 1; g = idx - 24; }
    else if (idx < 72) { c = 2; g = idx - 40; }
    else               { c = 3; g = idx - 48; }
    int qb = 4 * g + w;                  // this wave's q-tile
    int m0 = qb * 16;
    int Bq = (qb < 32) ? qb : (qb < 64) ? 2*qb - 32 : (qb < 96) ? 3*qb - 96 : 4*qb - 192;
    int pid = b * 320 + Bq + c;

    const ushort* Qb = Qw + (size_t)b * TT * HDIM;
    const ushort* Kb = Kw + (size_t)b * TT * HDIM;
    const ushort* Vb = Vtw + (size_t)b * HDIM * TT;

    __shared__ ushort KVb[2][8][512];          // 16 KB shared double buffer
    __shared__ __hip_bfloat16 Pls[4][16][40];  //  5 KB per-wave P roundtrip

    // wave w stages frags 2w, 2w+1 of {k0l,k0h,k1l,k1h,v0,v1,v2,v3}
    auto stageKV = [&](int buf, int s) {
        #pragma unroll
        for (int j = 0; j < 2; ++j) {
            int f = w * 2 + j;
            const ushort* gp;
            if (f < 4) {
                int half = f & 1;
                int ro   = (f >> 1) * 16;
                gp = Kb + (size_t)(s + ro + col) * HDIM + half * 32 + quad * 8;
            } else {
                int vg = f - 4;
                gp = Vb + (size_t)(vg * 16 + col) * TT + s + quad * 8;
            }
            gl_lds16(gp, &KVb[buf][f][0]);
        }
    };

    bf16x8 qf0 = ldb8(Qb + (size_t)(m0 + col) * HDIM + quad * 8);
    bf16x8 qf1 = ldb8(Qb + (size_t)(m0 + col) * HDIM + 32 + quad * 8);

    f32x4 o0 = {0.f,0.f,0.f,0.f};
    f32x4 o1 = {0.f,0.f,0.f,0.f};
    f32x4 o2 = {0.f,0.f,0.f,0.f};
    f32x4 o3 = {0.f,0.f,0.f,0.f};
    float rsum[4] = {0.f, 0.f, 0.f, 0.f};

    const int start = c * 512;
    const int end   = min(start + 512, 64 * g + 64);   // block-uniform

    stageKV(0, start);
    for (int s0 = start; s0 < end; s0 += 32) {
        int p  = ((s0 - start) >> 5) & 1;
        int sn = (s0 + 32 < end) ? s0 + 32 : s0;
        stageKV(p ^ 1, sn);
        __builtin_amdgcn_s_waitcnt(WCNT_VM2);   // own step-i DMAs done
        __builtin_amdgcn_s_barrier();           // whole buf[p] staged

        if (s0 < m0 + 16) {                     // wave-uniform causal skip
            bf16x8 ck0l = ldb8(&KVb[p][0][lane * 8]);
            bf16x8 ck0h = ldb8(&KVb[p][1][lane * 8]);
            bf16x8 ck1l = ldb8(&KVb[p][2][lane * 8]);
            bf16x8 ck1h = ldb8(&KVb[p][3][lane * 8]);

            f32x4 S0 = {0.f,0.f,0.f,0.f};
            f32x4 S1 = {0.f,0.f,0.f,0.f};
            S0 = __builtin_amdgcn_mfma_f32_16x16x32_bf16(qf0, ck0l, S0, 0, 0, 0);
            S0 = __builtin_amdgcn_mfma_f32_16x16x32_bf16(qf1, ck0h, S0, 0, 0, 0);
            S1 = __builtin_amdgcn_mfma_f32_16x16x32_bf16(qf0, ck1l, S1, 0, 0, 0);
            S1 = __builtin_amdgcn_mfma_f32_16x16x32_bf16(qf1, ck1h, S1, 0, 0, 0);

            #pragma unroll
            for (int r = 0; r < 4; ++r) {
                int trow = m0 + quad * 4 + r;
                float aa = (s0 + col      > trow) ? -1e30f : S0[r];
                float dd = (s0 + 16 + col > trow) ? -1e30f : S1[r];
                float p0 = exp2f(aa);
                float p1 = exp2f(dd);
                rsum[r] += p0 + p1;
                Pls[w][quad * 4 + r][col]      = __float2bfloat16(p0);
                Pls[w][quad * 4 + r][16 + col] = __float2bfloat16(p1);
            }
            bf16x8 pf = *reinterpret_cast<const bf16x8*>(&Pls[w][col][quad * 8]);

            bf16x8 cv0 = ldb8(&KVb[p][4][lane * 8]);
            bf16x8 cv1 = ldb8(&KVb[p][5][lane * 8]);
            bf16x8 cv2 = ldb8(&KVb[p][6][lane * 8]);
            bf16x8 cv3 = ldb8(&KVb[p][7][lane * 8]);
            o0 = __builtin_amdgcn_mfma_f32_16x16x32_bf16(pf, cv0, o0, 0, 0, 0);
            o1 = __builtin_amdgcn_mfma_f32_16x16x32_bf16(pf, cv1, o1, 0, 0, 0);
            o2 = __builtin_amdgcn_mfma_f32_16x16x32_bf16(pf, cv2, o2, 0, 0, 0);
            o3 = __builtin_amdgcn_mfma_f32_16x16x32_bf16(pf, cv3, o3, 0, 0, 0);
        }
        __builtin_amdgcn_s_waitcnt(WCNT_LGKM0); // buf[p] reads complete
        __builtin_amdgcn_s_barrier();           // before buf[p] re-stage
    }

    #pragma unroll
    for (int off = 1; off < 16; off <<= 1) {
        #pragma unroll
        for (int r = 0; r < 4; ++r)
            rsum[r] += __shfl_xor(rsum[r], off, 64);
    }

    ushort* pb = Po + (size_t)pid * 1024;
    #pragma unroll
    for (int r = 0; r < 4; ++r) {
        int row = quad * 4 + r;
        pb[row * 64 + 0*16 + col] = f2bf_bits(o0[r]);
        pb[row * 64 + 1*16 + col] = f2bf_bits(o1[r]);
        pb[row * 64 + 2*16 + col] = f2bf_bits(o2[r]);
        pb[row * 64 + 3*16 + col] = f2bf_bits(o3[r]);
        if (col == 0) Pl[pid * 16 + row] = rsum[r];
    }
}

// ---------------------------------------------------------------------------
// Kernel 4: merge <=4 chunk partials (plain sum, shared implicit max=0),
// normalize by total L, store out.  One wave per (b,qb).
// ---------------------------------------------------------------------------
__global__ __launch_bounds__(256) void k_merge(const ushort* __restrict__ x,
                                               const ushort* __restrict__ Po,
                                               const float* __restrict__ Pl,
                                               void* __restrict__ outv) {
    int f32m = probe_f32(x);
    int wid  = blockIdx.x * 4 + (threadIdx.x >> 6);  // 0..1023
    int lane = threadIdx.x & 63;
    int row  = lane >> 2;
    int g    = lane & 3;
    int b    = wid >> 7;
    int qb   = wid & 127;
    int nch  = (qb >> 5) + 1;
    int Bq   = (qb < 32) ? qb : (qb < 64) ? 2*qb - 32 : (qb < 96) ? 3*qb - 96 : 4*qb - 192;
    int pid0 = b * 320 + Bq;

    float L = 0.f;
    #pragma unroll
    for (int c = 0; c < 4; ++c)
        if (c < nch) L += Pl[(pid0 + c) * 16 + row];
    float inv = 1.0f / L;

    float o[16];
    #pragma unroll
    for (int j = 0; j < 16; ++j) o[j] = 0.f;
    #pragma unroll
    for (int c = 0; c < 4; ++c) {
        if (c < nch) {
            const ushort* p = Po + (size_t)(pid0 + c) * 1024 + row * 64 + g * 16;
            bf16x8 v0 = ldb8(p);
            bf16x8 v1 = ldb8(p + 8);
            #pragma unroll
            for (int j = 0; j < 8; ++j) {
                o[j]     += (float)v0[j];
                o[8 + j] += (float)v1[j];
            }
        }
    }

    size_t obase = ((size_t)b * TT + qb * 16 + row) * HDIM + g * 16;
    if (f32m) {
        float* ob = (float*)outv + obase;
        #pragma unroll
        for (int j = 0; j < 16; ++j) ob[j] = o[j] * inv;
    } else {
        ushort* ob = (ushort*)outv + obase;
        #pragma unroll
        for (int j = 0; j < 16; ++j) ob[j] = f2bf_bits(o[j] * inv);
    }
}

// ---------------------------------------------------------------------------
extern "C" void kernel_launch(void* const* d_in, const int* in_sizes, int n_in,
                              void* d_out, int out_size, void* d_ws, size_t ws_size,
                              hipStream_t stream) {
    const ushort* x = (const ushort*)d_in[0];
    ushort* Wt  = (ushort*)d_ws;                       // 196608 elts
    ushort* Qw  = Wt + 3 * HDIM * DD;
    ushort* Kw  = Qw + (size_t)NB * TT * HDIM;
    ushort* Vtw = Kw + (size_t)NB * TT * HDIM;
    ushort* Po  = Vtw + (size_t)NB * TT * HDIM;        // 2560*1024 ushorts
    float*  Pl  = (float*)(Po + (size_t)2560 * 1024);  // ~12.2 MB total

    k_wt   <<<768, 256, 0, stream>>>(x, d_in[1], d_in[2], d_in[3], Wt);
    k_proj <<<768, 256, 0, stream>>>(d_in[0], Wt, Qw, Kw, Vtw);
    k_attn <<<640, 256, 0, stream>>>(Qw, Kw, Vtw, Po, Pl);
    k_merge<<<256, 256, 0, stream>>>(x, Po, Pl, d_out);
}

// Round 10
// 155.704 us; speedup vs baseline: 1.2178x; 1.0181x over previous
//
#include <hip/hip_runtime.h>
#include <hip/hip_bf16.h>
#include <stdint.h>

#define NB 8
#define TT 2048
#define DD 1024
#define HDIM 64

typedef __bf16 bf16x8 __attribute__((ext_vector_type(8)));
typedef float f32x4 __attribute__((ext_vector_type(4)));

static_assert(sizeof(bf16x8) == 16, "bf16x8 must be 16 bytes");

__device__ inline ushort f2bf_bits(float f) {
    __hip_bfloat16 h = __float2bfloat16(f);
    return *reinterpret_cast<ushort*>(&h);
}
__device__ inline float bfbits2f(ushort u) {
    unsigned v = ((unsigned)u) << 16;
    return __builtin_bit_cast(float, v);
}
__device__ inline bf16x8 ldb8(const ushort* p) {
    return *reinterpret_cast<const bf16x8*>(p);
}

// async global->LDS DMA, 16B/lane: dest = wave-uniform base + lane*16.
typedef __attribute__((address_space(3))) uint32_t lds_u32;
typedef const __attribute__((address_space(1))) uint32_t glb_u32;
__device__ inline void gl_lds16(const void* g, void* l) {
    __builtin_amdgcn_global_load_lds((glb_u32*)g, (lds_u32*)l, 16, 0, 0);
}

// s_waitcnt immediates (gfx9: vm[3:0]+[15:14], exp[6:4], lgkm[11:8])
#define WCNT_VM2   0xF72   // vmcnt(2)
#define WCNT_VM3   0xF73   // vmcnt(3)
#define WCNT_VM4   0xF74   // vmcnt(4)
#define WCNT_LGKM0 0xC07F  // lgkmcnt(0), vmcnt/expcnt unconstrained

// ---------------------------------------------------------------------------
// Inline dtype probe: f32 x -> even halfwords show wild bf16 exponents.
// ---------------------------------------------------------------------------
__device__ inline int probe_f32(const ushort* x) {
    int lane = threadIdx.x & 63;
    int wild = 0;
    #pragma unroll
    for (int j = 0; j < 4; ++j) {
        ushort u = x[(lane * 4 + j) * 32];
        int e = (u >> 7) & 0xFF;
        wild += (e >= 0xC0);
    }
    unsigned long long m = __ballot(wild > 0);
    return __popcll(m) > 8;
}

// ---------------------------------------------------------------------------
// Kernel 1: pack weights -> Wt[192][1024] bf16 (row = global out-col, k
// contiguous).  Softmax scale * log2(e) folded into Wq (exp2 domain).
// ---------------------------------------------------------------------------
__global__ __launch_bounds__(256) void k_wt(const ushort* __restrict__ x,
                                            const void* __restrict__ Wq,
                                            const void* __restrict__ Wk,
                                            const void* __restrict__ Wv,
                                            ushort* __restrict__ Wt) {
    int f32m = probe_f32(x);
    int idx = blockIdx.x * 256 + threadIdx.x;   // 0 .. 196607
    int mat = idx >> 16;
    int rem = idx & 65535;                      // = d*64 + h
    int d = rem >> 6;
    int h = rem & 63;
    const void* W = (mat == 0) ? Wq : (mat == 1) ? Wk : Wv;
    float v;
    if (f32m) v = ((const float*)W)[rem];
    else      v = bfbits2f(((const ushort*)W)[rem]);
    if (mat == 0) v *= 0.18033688011112042f;    // 0.125 * log2(e)
    Wt[(size_t)mat * 65536 + (size_t)h * DD + d] = f2bf_bits(v);
}

// ---------------------------------------------------------------------------
// Kernel 2: QKV projection, x fetched ONCE.  512 blocks x 512 threads
// (8 waves); block = 32 rows x ALL 192 cols.  Wave = 16 rows (mt=w>>2) x
// 48 cols (nh=w&3), 3 accs.  BK=64 double-buffered LDS DMA (48KB B + 16KB A
// = 64KB -> 2 blocks/CU = 16 waves/CU), vmcnt crossing raw s_barrier.
// ---------------------------------------------------------------------------
template <int F32M>
__device__ inline void proj_body(const void* __restrict__ xv,
                                 const ushort* __restrict__ Wt,
                                 ushort* __restrict__ Qw,
                                 ushort* __restrict__ Kw,
                                 ushort* __restrict__ Vtw,
                                 ushort* Bf, float* Af) {
    int tid  = threadIdx.x;
    int w    = tid >> 6;                 // 0..7
    int lane = tid & 63;
    int quad = lane >> 4;
    int col  = lane & 15;
    int mt   = w >> 2;                   // m-tile 0..1
    int nh   = w & 3;                    // n-strip 0..3 (48 cols)
    int m0   = blockIdx.x * 32;

    ushort* Afb = (ushort*)Af;           // bf16 path aliases the A buffer

    auto stage = [&](int buf, int kkk) {
        #pragma unroll
        for (int j = 0; j < 3; ++j) {
            int f  = w * 3 + j;          // 0..23 = nt*2+ks
            int nt = f >> 1, ks = f & 1;
            gl_lds16(Wt + (size_t)(nt * 16 + col) * DD + kkk + ks * 32 + quad * 8,
                     Bf + ((size_t)buf * 24 + f) * 512);
        }
        if (F32M) {
            int amt = w >> 2, ks = (w >> 1) & 1, hf = w & 1;   // 8 frags, 1/wave
            gl_lds16((const float*)xv + (size_t)(m0 + amt * 16 + col) * DD
                         + kkk + ks * 32 + hf * 4 + quad * 8,
                     Af + ((((buf * 2 + amt) * 2 + ks) * 2) + hf) * 256);
        } else if (w < 4) {
            int amt = w >> 1, ks = w & 1;                      // 4 frags, waves 0-3
            gl_lds16((const ushort*)xv + (size_t)(m0 + amt * 16 + col) * DD
                         + kkk + ks * 32 + quad * 8,
                     Afb + (((buf * 2 + amt) * 2) + ks) * 512);
        }
    };

    f32x4 acc[3];
    #pragma unroll
    for (int i = 0; i < 3; ++i) acc[i] = (f32x4){0.f,0.f,0.f,0.f};

    stage(0, 0);
    for (int kk = 0; kk < DD; kk += 64) {
        int p  = (kk >> 6) & 1;
        int kn = (kk + 64 < DD) ? kk + 64 : kk;
        stage(p ^ 1, kn);
        if (F32M) {
            __builtin_amdgcn_s_waitcnt(WCNT_VM4);   // own 4 chunk-k DMAs done
        } else {
            if (w < 4) __builtin_amdgcn_s_waitcnt(WCNT_VM4);
            else       __builtin_amdgcn_s_waitcnt(WCNT_VM3);
        }
        __builtin_amdgcn_s_barrier();

        #pragma unroll
        for (int ks = 0; ks < 2; ++ks) {
            bf16x8 a;
            if (F32M) {
                f32x4 alo = *reinterpret_cast<const f32x4*>(Af + ((((p * 2 + mt) * 2 + ks) * 2) + 0) * 256 + lane * 4);
                f32x4 ahi = *reinterpret_cast<const f32x4*>(Af + ((((p * 2 + mt) * 2 + ks) * 2) + 1) * 256 + lane * 4);
                #pragma unroll
                for (int j = 0; j < 4; ++j) { a[j] = (__bf16)alo[j]; a[4+j] = (__bf16)ahi[j]; }
            } else {
                a = ldb8(Afb + (((p * 2 + mt) * 2) + ks) * 512 + lane * 8);
            }
            #pragma unroll
            for (int j = 0; j < 3; ++j) {
                int nt = nh * 3 + j;
                bf16x8 b = ldb8(Bf + ((size_t)p * 24 + nt * 2 + ks) * 512 + lane * 8);
                acc[j] = __builtin_amdgcn_mfma_f32_16x16x32_bf16(a, b, acc[j], 0, 0, 0);
            }
        }
        __builtin_amdgcn_s_waitcnt(WCNT_LGKM0);   // buf[p] reads complete
        __builtin_amdgcn_s_barrier();             // before buf[p] re-stage
    }

    // C/D layout: row = quad*4 + reg, col = lane&15
    #pragma unroll
    for (int j = 0; j < 3; ++j) {
        int nt  = nh * 3 + j;
        int mat = nt >> 2;                 // 0=Q,1=K,2=V
        int h   = (nt & 3) * 16 + col;
        if (mat == 2) {
            #pragma unroll
            for (int r = 0; r < 4; ++r) {
                int row = m0 + mt * 16 + quad * 4 + r;
                int bb = row >> 11;
                int t  = row & (TT - 1);
                Vtw[(size_t)bb * HDIM * TT + (size_t)h * TT + t] = f2bf_bits(acc[j][r]);
            }
        } else {
            ushort* outp = (mat == 0) ? Qw : Kw;
            #pragma unroll
            for (int r = 0; r < 4; ++r) {
                int row = m0 + mt * 16 + quad * 4 + r;
                outp[(size_t)row * HDIM + h] = f2bf_bits(acc[j][r]);
            }
        }
    }
}

__global__ __launch_bounds__(512) void k_proj(const void* __restrict__ xv,
                                              const ushort* __restrict__ Wt,
                                              ushort* __restrict__ Qw,
                                              ushort* __restrict__ Kw,
                                              ushort* __restrict__ Vtw) {
    __shared__ ushort Bf[2 * 24 * 512];        // 48 KB
    __shared__ float  Af[2 * 2 * 2 * 2 * 256]; // 16 KB (bf16 path aliases)
    if (probe_f32((const ushort*)xv)) proj_body<1>(xv, Wt, Qw, Kw, Vtw, Bf, Af);
    else                              proj_body<0>(xv, Wt, Qw, Kw, Vtw, Bf, Af);
}

// ---------------------------------------------------------------------------
// Kernel 3: split-K causal flash attention, BLOCK-SHARED K/V staging.
// Block = (b, q-group of 4 tiles, 512-key chunk); 4 waves each own one
// q-tile, sharing one double-buffered K/V stream (16 KB).  2 DMAs/wave/step,
// vmcnt(2) across barrier.  640 blocks, ~21 KB LDS -> all co-resident.
// ---------------------------------------------------------------------------
__global__ __launch_bounds__(256) void k_attn(const ushort* __restrict__ Qw,
                                              const ushort* __restrict__ Kw,
                                              const ushort* __restrict__ Vtw,
                                              ushort* __restrict__ Po,
                                              float* __restrict__ Pl) {
    int w    = threadIdx.x >> 6;
    int lane = threadIdx.x & 63;
    int quad = lane >> 4;
    int col  = lane & 15;
    int bid  = blockIdx.x;               // 0..639
    int b    = bid & 7;
    int idx  = 79 - (bid >> 3);          // longer blocks earlier-ish
    int c, g;
    if (idx < 32)      { c = 0; g = idx; }
    else if (idx < 56) { c = 1; g = idx - 24; }
    else if (idx < 72) { c = 2; g = idx - 40; }
    else               { c = 3; g = idx - 48; }
    int qb = 4 * g + w;                  // this wave's q-tile
    int m0 = qb * 16;
    int Bq = (qb < 32) ? qb : (qb < 64) ? 2*qb - 32 : (qb < 96) ? 3*qb - 96 : 4*qb - 192;
    int pid = b * 320 + Bq + c;

    const ushort* Qb = Qw + (size_t)b * TT * HDIM;
    const ushort* Kb = Kw + (size_t)b * TT * HDIM;
    const ushort* Vb = Vtw + (size_t)b * HDIM * TT;

    __shared__ ushort KVb[2][8][512];          // 16 KB shared double buffer
    __shared__ __hip_bfloat16 Pls[4][16][40];  //  5 KB per-wave P roundtrip

    // wave w stages frags 2w, 2w+1 of {k0l,k0h,k1l,k1h,v0,v1,v2,v3}
    auto stageKV = [&](int buf, int s) {
        #pragma unroll
        for (int j = 0; j < 2; ++j) {
            int f = w * 2 + j;
            const ushort* gp;
            if (f < 4) {
                int half = f & 1;
                int ro   = (f >> 1) * 16;
                gp = Kb + (size_t)(s + ro + col) * HDIM + half * 32 + quad * 8;
            } else {
                int vg = f - 4;
                gp = Vb + (size_t)(vg * 16 + col) * TT + s + quad * 8;
            }
            gl_lds16(gp, &KVb[buf][f][0]);
        }
    };

    bf16x8 qf0 = ldb8(Qb + (size_t)(m0 + col) * HDIM + quad * 8);
    bf16x8 qf1 = ldb8(Qb + (size_t)(m0 + col) * HDIM + 32 + quad * 8);

    f32x4 o0 = {0.f,0.f,0.f,0.f};
    f32x4 o1 = {0.f,0.f,0.f,0.f};
    f32x4 o2 = {0.f,0.f,0.f,0.f};
    f32x4 o3 = {0.f,0.f,0.f,0.f};
    float rsum[4] = {0.f, 0.f, 0.f, 0.f};

    const int start = c * 512;
    const int end   = min(start + 512, 64 * g + 64);   // block-uniform

    stageKV(0, start);
    for (int s0 = start; s0 < end; s0 += 32) {
        int p  = ((s0 - start) >> 5) & 1;
        int sn = (s0 + 32 < end) ? s0 + 32 : s0;
        stageKV(p ^ 1, sn);
        __builtin_amdgcn_s_waitcnt(WCNT_VM2);   // own step-i DMAs done
        __builtin_amdgcn_s_barrier();           // whole buf[p] staged

        if (s0 < m0 + 16) {                     // wave-uniform causal skip
            bf16x8 ck0l = ldb8(&KVb[p][0][lane * 8]);
            bf16x8 ck0h = ldb8(&KVb[p][1][lane * 8]);
            bf16x8 ck1l = ldb8(&KVb[p][2][lane * 8]);
            bf16x8 ck1h = ldb8(&KVb[p][3][lane * 8]);

            f32x4 S0 = {0.f,0.f,0.f,0.f};
            f32x4 S1 = {0.f,0.f,0.f,0.f};
            S0 = __builtin_amdgcn_mfma_f32_16x16x32_bf16(qf0, ck0l, S0, 0, 0, 0);
            S0 = __builtin_amdgcn_mfma_f32_16x16x32_bf16(qf1, ck0h, S0, 0, 0, 0);
            S1 = __builtin_amdgcn_mfma_f32_16x16x32_bf16(qf0, ck1l, S1, 0, 0, 0);
            S1 = __builtin_amdgcn_mfma_f32_16x16x32_bf16(qf1, ck1h, S1, 0, 0, 0);

            #pragma unroll
            for (int r = 0; r < 4; ++r) {
                int trow = m0 + quad * 4 + r;
                float aa = (s0 + col      > trow) ? -1e30f : S0[r];
                float dd = (s0 + 16 + col > trow) ? -1e30f : S1[r];
                float p0 = exp2f(aa);
                float p1 = exp2f(dd);
                rsum[r] += p0 + p1;
                Pls[w][quad * 4 + r][col]      = __float2bfloat16(p0);
                Pls[w][quad * 4 + r][16 + col] = __float2bfloat16(p1);
            }
            bf16x8 pf = *reinterpret_cast<const bf16x8*>(&Pls[w][col][quad * 8]);

            bf16x8 cv0 = ldb8(&KVb[p][4][lane * 8]);
            bf16x8 cv1 = ldb8(&KVb[p][5][lane * 8]);
            bf16x8 cv2 = ldb8(&KVb[p][6][lane * 8]);
            bf16x8 cv3 = ldb8(&KVb[p][7][lane * 8]);
            o0 = __builtin_amdgcn_mfma_f32_16x16x32_bf16(pf, cv0, o0, 0, 0, 0);
            o1 = __builtin_amdgcn_mfma_f32_16x16x32_bf16(pf, cv1, o1, 0, 0, 0);
            o2 = __builtin_amdgcn_mfma_f32_16x16x32_bf16(pf, cv2, o2, 0, 0, 0);
            o3 = __builtin_amdgcn_mfma_f32_16x16x32_bf16(pf, cv3, o3, 0, 0, 0);
        }
        __builtin_amdgcn_s_waitcnt(WCNT_LGKM0); // buf[p] reads complete
        __builtin_amdgcn_s_barrier();           // before buf[p] re-stage
    }

    #pragma unroll
    for (int off = 1; off < 16; off <<= 1) {
        #pragma unroll
        for (int r = 0; r < 4; ++r)
            rsum[r] += __shfl_xor(rsum[r], off, 64);
    }

    ushort* pb = Po + (size_t)pid * 1024;
    #pragma unroll
    for (int r = 0; r < 4; ++r) {
        int row = quad * 4 + r;
        pb[row * 64 + 0*16 + col] = f2bf_bits(o0[r]);
        pb[row * 64 + 1*16 + col] = f2bf_bits(o1[r]);
        pb[row * 64 + 2*16 + col] = f2bf_bits(o2[r]);
        pb[row * 64 + 3*16 + col] = f2bf_bits(o3[r]);
        if (col == 0) Pl[pid * 16 + row] = rsum[r];
    }
}

// ---------------------------------------------------------------------------
// Kernel 4: merge <=4 chunk partials (plain sum, shared implicit max=0),
// normalize by total L, store out.  One wave per (b,qb).
// ---------------------------------------------------------------------------
__global__ __launch_bounds__(256) void k_merge(const ushort* __restrict__ x,
                                               const ushort* __restrict__ Po,
                                               const float* __restrict__ Pl,
                                               void* __restrict__ outv) {
    int f32m = probe_f32(x);
    int wid  = blockIdx.x * 4 + (threadIdx.x >> 6);  // 0..1023
    int lane = threadIdx.x & 63;
    int row  = lane >> 2;
    int g    = lane & 3;
    int b    = wid >> 7;
    int qb   = wid & 127;
    int nch  = (qb >> 5) + 1;
    int Bq   = (qb < 32) ? qb : (qb < 64) ? 2*qb - 32 : (qb < 96) ? 3*qb - 96 : 4*qb - 192;
    int pid0 = b * 320 + Bq;

    float L = 0.f;
    #pragma unroll
    for (int c = 0; c < 4; ++c)
        if (c < nch) L += Pl[(pid0 + c) * 16 + row];
    float inv = 1.0f / L;

    float o[16];
    #pragma unroll
    for (int j = 0; j < 16; ++j) o[j] = 0.f;
    #pragma unroll
    for (int c = 0; c < 4; ++c) {
        if (c < nch) {
            const ushort* p = Po + (size_t)(pid0 + c) * 1024 + row * 64 + g * 16;
            bf16x8 v0 = ldb8(p);
            bf16x8 v1 = ldb8(p + 8);
            #pragma unroll
            for (int j = 0; j < 8; ++j) {
                o[j]     += (float)v0[j];
                o[8 + j] += (float)v1[j];
            }
        }
    }

    size_t obase = ((size_t)b * TT + qb * 16 + row) * HDIM + g * 16;
    if (f32m) {
        float* ob = (float*)outv + obase;
        #pragma unroll
        for (int j = 0; j < 16; ++j) ob[j] = o[j] * inv;
    } else {
        ushort* ob = (ushort*)outv + obase;
        #pragma unroll
        for (int j = 0; j < 16; ++j) ob[j] = f2bf_bits(o[j] * inv);
    }
}

// ---------------------------------------------------------------------------
extern "C" void kernel_launch(void* const* d_in, const int* in_sizes, int n_in,
                              void* d_out, int out_size, void* d_ws, size_t ws_size,
                              hipStream_t stream) {
    const ushort* x = (const ushort*)d_in[0];
    ushort* Wt  = (ushort*)d_ws;                       // 196608 elts
    ushort* Qw  = Wt + 3 * HDIM * DD;
    ushort* Kw  = Qw + (size_t)NB * TT * HDIM;
    ushort* Vtw = Kw + (size_t)NB * TT * HDIM;
    ushort* Po  = Vtw + (size_t)NB * TT * HDIM;        // 2560*1024 ushorts
    float*  Pl  = (float*)(Po + (size_t)2560 * 1024);  // ~12.2 MB total

    k_wt   <<<768, 256, 0, stream>>>(x, d_in[1], d_in[2], d_in[3], Wt);
    k_proj <<<512, 512, 0, stream>>>(d_in[0], Wt, Qw, Kw, Vtw);
    k_attn <<<640, 256, 0, stream>>>(Qw, Kw, Vtw, Po, Pl);
    k_merge<<<256, 256, 0, stream>>>(x, Po, Pl, d_out);
}